// Round 2
// baseline (152.482 us; speedup 1.0000x reference)
//
#include <hip/hip_runtime.h>
#include <hip/hip_bf16.h>
#include <stdint.h>

// Problem constants (B=8, S=2048, E=1024, H=128, DK=8)
#define M_DIM 16384   // B*S
#define N_DIM 1024    // E (output features)
#define K_DIM 1024    // E (reduction)

typedef __attribute__((ext_vector_type(8))) short short8;
typedef __attribute__((ext_vector_type(4))) float f32x4;

// async global->LDS, 16B per lane. LDS dest must be wave-uniform base + lane*16.
#define GLD_LDS(g, l) __builtin_amdgcn_global_load_lds( \
    (const __attribute__((address_space(1))) unsigned int*)(g), \
    (__attribute__((address_space(3))) unsigned int*)(l), 16, 0, 0)

__device__ __forceinline__ unsigned short f2bf(float f) {
  union { float f; unsigned int u; } v;
  v.f = f;
  unsigned int u = v.u + 0x7FFFu + ((v.u >> 16) & 1u);  // RNE
  return (unsigned short)(u >> 16);
}

// Fused prep: blocks [0, 8192) -> A_bf16[m,k] = bf16(cos(x[m,k]+theta[k]));
//             blocks [8192, 8704) -> W_bf16 cast. 8 elems/thread, all 16B I/O.
#define PREP_A_BLOCKS (M_DIM * K_DIM / (256 * 8))   // 8192
#define PREP_W_BLOCKS (N_DIM * K_DIM / (256 * 8))   // 512
__global__ __launch_bounds__(256) void prep_all(const float* __restrict__ x,
                                                const float* __restrict__ theta,
                                                const float* __restrict__ W,
                                                unsigned short* __restrict__ A,
                                                unsigned short* __restrict__ Wb) {
  if (blockIdx.x < PREP_A_BLOCKS) {
    const long i = ((long)blockIdx.x * 256 + threadIdx.x) * 8;
    const int k = (int)(i & (K_DIM - 1));
    float4 x0 = *(const float4*)(x + i);
    float4 x1 = *(const float4*)(x + i + 4);
    float4 t0 = *(const float4*)(theta + k);
    float4 t1 = *(const float4*)(theta + k + 4);
    union { unsigned short s[8]; short8 v; } o;
    o.s[0] = f2bf(__cosf(x0.x + t0.x));
    o.s[1] = f2bf(__cosf(x0.y + t0.y));
    o.s[2] = f2bf(__cosf(x0.z + t0.z));
    o.s[3] = f2bf(__cosf(x0.w + t0.w));
    o.s[4] = f2bf(__cosf(x1.x + t1.x));
    o.s[5] = f2bf(__cosf(x1.y + t1.y));
    o.s[6] = f2bf(__cosf(x1.z + t1.z));
    o.s[7] = f2bf(__cosf(x1.w + t1.w));
    *(short8*)(A + i) = o.v;
  } else {
    const long i = ((long)(blockIdx.x - PREP_A_BLOCKS) * 256 + threadIdx.x) * 8;
    float4 w0 = *(const float4*)(W + i);
    float4 w1 = *(const float4*)(W + i + 4);
    union { unsigned short s[8]; short8 v; } o;
    o.s[0] = f2bf(w0.x); o.s[1] = f2bf(w0.y); o.s[2] = f2bf(w0.z); o.s[3] = f2bf(w0.w);
    o.s[4] = f2bf(w1.x); o.s[5] = f2bf(w1.y); o.s[6] = f2bf(w1.z); o.s[7] = f2bf(w1.w);
    *(short8*)(Wb + i) = o.v;
  }
}

// C[m,n] = sum_k A[m,k]*Bt[n,k] + bias[n].  A:[M,K] bf16, Bt:[N,K] bf16, C:[M,N] f32.
//
// 256x256 tile, BK=64, 8 waves (2M x 4N, 128x64 per wave), 512 THREADS
// (r3 bug: launched with 256 threads -> half of LDS unstaged -> NaN).
// LDS 128 KB: A/B K-tiles double-buffered. 2-deep counted-vmcnt pipeline:
// tile t+1's 8 global_load_lds are issued BEFORE computing tile t; we wait
// vmcnt(8) (tile t's loads landed, t+1's still in flight) -> staging latency
// hides under MFMA. Raw s_barrier (NOT __syncthreads) so the compiler does not
// drain vmcnt(0) at the barrier. Per K-tile: 2 ks-phases with a barrier between
// (wave role split) + s_setprio(1) around each 32-MFMA cluster (T5).
// LDS XOR-chunk swizzle identical to the verified r2 layout (conflicts=0):
// LDS[row][slot s] = global[row][s ^ (row&7)], applied on BOTH sides (rule #21).
//
// Buffer safety: iter t stages into buf[cur^1]; that buffer's readers finished
// before iter t-1's end-of-tile barrier (ds_reads complete before the MFMAs
// that consume them, which precede the barrier). vmcnt(8) is per-wave; the
// following barrier makes all 8 waves' portions of buf[cur] visible before
// any ds_read.
//
// Grid: 256 blocks = exactly 1/CU (128 KB LDS). XCD-banded map: linear id L,
// XCD c = L&7 owns M-tiles [8c, 8c+8); the 4 N-blocks of an M-tile are
// adjacent in dispatch (share the A panel in that XCD's L2).
__global__ __launch_bounds__(512, 2) void gemm_bt(const unsigned short* __restrict__ A,
                                                  const unsigned short* __restrict__ Bt,
                                                  const float* __restrict__ bias,
                                                  float* __restrict__ C) {
  constexpr int BM = 256, BN = 256, BK = 64;
  constexpr int NT = K_DIM / BK;  // 16
  __shared__ unsigned short As[2 * BM * BK];  // 64 KB (2 buffers)
  __shared__ unsigned short Bs[2 * BN * BK];  // 64 KB
  const int tid = threadIdx.x;

  const int L = blockIdx.y * 4 + blockIdx.x;  // linear dispatch id, 0..255
  const int xcd = L & 7;
  const int idx = L >> 3;                     // 0..31 within XCD
  const int by = xcd * 8 + (idx >> 2);        // M-tile 0..63, banded per XCD
  const int bx = idx & 3;                     // N-tile 0..3
  const int m0 = by * BM;
  const int n0 = bx * BN;

  const int lane = tid & 63;
  const int wave = tid >> 6;        // 0..7
  const int wm = (wave >> 2) * 128; // wave tile origin in M (0,128)
  const int wn = (wave & 3) * 64;   // wave tile origin in N (0,64,128,192)
  const int fr = lane & 15;         // row within 16x16 frag
  const int fq = lane >> 4;         // quarter-wave 0..3

  f32x4 acc[8][4] = {};

  // Staging: per issue i (0..3), thread t fills LDS slot d = i*512 + t
  // (8 bf16 chunk). row = d>>3 = i*64 + (t>>3); source chunk is XOR-swizzled:
  // LDS[row][slot s] = global[row][s ^ (row&7)]. row&7 == (t>>3)&7 for all i.
  const int csw = (tid & 7) ^ ((tid >> 3) & 7);
  const unsigned short* Ag = A + (long)(m0 + (tid >> 3)) * K_DIM + csw * 8;
  const unsigned short* Bg = Bt + (long)(n0 + (tid >> 3)) * K_DIM + csw * 8;
  unsigned short* Asd = As + tid * 8;
  unsigned short* Bsd = Bs + tid * 8;

  // prologue: stage tile 0 into buffer 0
#pragma unroll
  for (int i = 0; i < 4; ++i) GLD_LDS(Ag + (long)i * 64 * K_DIM, Asd + i * 4096);
#pragma unroll
  for (int i = 0; i < 4; ++i) GLD_LDS(Bg + (long)i * 64 * K_DIM, Bsd + i * 4096);
  Ag += BK;
  Bg += BK;

  for (int t = 0; t < NT; ++t) {
    const int cur = t & 1;
    if (t < NT - 1) {
      // issue next tile's 8 loads into the other buffer (not waited here)
      unsigned short* Ad = Asd + (cur ^ 1) * (BM * BK);
      unsigned short* Bd = Bsd + (cur ^ 1) * (BN * BK);
#pragma unroll
      for (int i = 0; i < 4; ++i) GLD_LDS(Ag + (long)i * 64 * K_DIM, Ad + i * 4096);
#pragma unroll
      for (int i = 0; i < 4; ++i) GLD_LDS(Bg + (long)i * 64 * K_DIM, Bd + i * 4096);
      Ag += BK;
      Bg += BK;
      asm volatile("s_waitcnt vmcnt(8)" ::: "memory");  // tile t landed (per-wave)
    } else {
      asm volatile("s_waitcnt vmcnt(0)" ::: "memory");  // last tile: drain
    }
    __builtin_amdgcn_s_barrier();  // all waves' portions of buf[cur] visible
    asm volatile("" ::: "memory");

    const unsigned short* SA = As + cur * (BM * BK);
    const unsigned short* SB = Bs + cur * (BN * BK);
#pragma unroll
    for (int ks = 0; ks < 2; ++ks) {
      // chunk slot for this lane: (k-chunk) ^ (row&7); row&7 == lane&7 for all
      // frag rows (wm, wn, i*16 are multiples of 8/16).
      const int swz = (((ks * 4 + fq) ^ (lane & 7)) * 8);
      short8 af[8], bf[4];
#pragma unroll
      for (int j = 0; j < 4; ++j)
        bf[j] = *(const short8*)(SB + (wn + j * 16 + fr) * BK + swz);
#pragma unroll
      for (int i = 0; i < 8; ++i)
        af[i] = *(const short8*)(SA + (wm + i * 16 + fr) * BK + swz);
      __builtin_amdgcn_s_setprio(1);
#pragma unroll
      for (int i = 0; i < 8; ++i)
#pragma unroll
        for (int j = 0; j < 4; ++j)
          acc[i][j] = __builtin_amdgcn_mfma_f32_16x16x32_bf16(af[i], bf[j], acc[i][j], 0, 0, 0);
      __builtin_amdgcn_s_setprio(0);
      if (ks == 0) {
        asm volatile("" ::: "memory");
        __builtin_amdgcn_s_barrier();  // phase split (wave role diversity)
        asm volatile("" ::: "memory");
      }
    }
    asm volatile("" ::: "memory");
    __builtin_amdgcn_s_barrier();  // all reads of buf[cur] done -> reusable
    asm volatile("" ::: "memory");
  }

  // Epilogue: D[row=(lane>>4)*4+r][col=lane&15] per 16x16 frag (m89-verified).
  const int cn = lane & 15;
  const int rq = (lane >> 4) * 4;
#pragma unroll
  for (int j = 0; j < 4; ++j) {
    const int n = n0 + wn + j * 16 + cn;
    const float bv = bias[n];
#pragma unroll
    for (int i = 0; i < 8; ++i) {
      const long mb = (long)(m0 + wm + i * 16 + rq) * N_DIM + n;
#pragma unroll
      for (int r = 0; r < 4; ++r)
        C[mb + (long)r * N_DIM] = acc[i][j][r] + bv;
    }
  }
}

extern "C" void kernel_launch(void* const* d_in, const int* in_sizes, int n_in,
                              void* d_out, int out_size, void* d_ws, size_t ws_size,
                              hipStream_t stream) {
  const float* x = (const float*)d_in[0];      // [8,2048,1024]
  const float* theta = (const float*)d_in[1];  // [128,8] -> flat 1024
  const float* W = (const float*)d_in[2];      // [1024,1024]
  const float* b = (const float*)d_in[3];      // [1024]
  float* out = (float*)d_out;                  // [8,2048,1024] f32

  unsigned short* Abf = (unsigned short*)d_ws;                   // 33.5 MB
  unsigned short* Wbf = Abf + (size_t)M_DIM * K_DIM;             // +2 MB

  hipLaunchKernelGGL(prep_all, dim3(PREP_A_BLOCKS + PREP_W_BLOCKS), dim3(256), 0,
                     stream, x, theta, W, Abf, Wbf);
  hipLaunchKernelGGL(gemm_bt, dim3(N_DIM / 256, M_DIM / 256), dim3(512), 0, stream,
                     Abf, Wbf, b, out);
}